// Round 2
// baseline (513.909 us; speedup 1.0000x reference)
//
#include <hip/hip_runtime.h>
#include <hip/hip_bf16.h>

constexpr int B  = 16;
constexpr int C  = 128;
constexpr int H  = 128;
constexpr int W  = 128;
constexpr int CO = 256;
constexpr int HO = 64;
constexpr int WO = 64;

#define EPSV   1e-8f
#define SLOPE  0.2f

typedef short bf16x8 __attribute__((ext_vector_type(8)));
typedef float f32x4  __attribute__((ext_vector_type(4)));

__device__ __forceinline__ short f2bs(float v) {
    __hip_bfloat16 h = __float2bfloat16(v);
    return *(short*)&h;
}
__device__ __forceinline__ float bs2f(short s) {
    __hip_bfloat16 h = *(__hip_bfloat16*)&s;
    return __bfloat162float(h);
}

// ---------------------------------------------------------------------------
// demod: d[conv][b][o] = rsqrt(sum_{i,k}(w[o,i,k]*(s[b,i]+1))^2 + eps)
// ---------------------------------------------------------------------------
__global__ __launch_bounds__(128) void demod_kernel(
    const float* __restrict__ w1, const float* __restrict__ w2,
    const float* __restrict__ s1, const float* __restrict__ s2,
    float* __restrict__ d)
{
    int bid  = blockIdx.x;          // conv*2048 + b*128 + o
    int conv = bid >> 11;
    int b    = (bid >> 7) & 15;
    int o    = bid & 127;
    const float* w = conv ? w2 : w1;
    const float* s = conv ? s2 : s1;
    int i = threadIdx.x;
    float sv = s[b * C + i] + 1.0f;
    const float* wp = w + (o * C + i) * 9;
    float sum = 0.f;
    #pragma unroll
    for (int k = 0; k < 9; ++k) { float t = wp[k] * sv; sum += t * t; }
    #pragma unroll
    for (int off = 32; off; off >>= 1) sum += __shfl_down(sum, off);
    __shared__ float red[2];
    if ((threadIdx.x & 63) == 0) red[threadIdx.x >> 6] = sum;
    __syncthreads();
    if (threadIdx.x == 0) d[bid] = rsqrtf(red[0] + red[1] + EPSV);
}

// ---------------------------------------------------------------------------
// expand -> step-major weight tiling for a linear K-walk:
// wm[cb][step = tap*4 + icC][ocT=oc>>4][(oc&15)*32 + (ic&31)]   (bf16)
// step stride = 8*512 = 4096 shorts; whole step = contiguous 8 KB.
// ---------------------------------------------------------------------------
__global__ __launch_bounds__(256) void expand_kernel(
    const float* __restrict__ w1, const float* __restrict__ w2,
    const float* __restrict__ s1, const float* __restrict__ s2,
    const float* __restrict__ d, short* __restrict__ wm)
{
    int idx = blockIdx.x * 256 + threadIdx.x;
    int ic  = idx & 127;
    int oc  = (idx >> 7) & 127;
    int t   = idx >> 14;            // cb*9+tap, < 288
    int tap = t % 9;
    int cb  = t / 9;                // conv*16+b
    int b   = cb & 15;
    int conv= cb >> 4;
    const float* w = conv ? w2 : w1;
    const float* s = conv ? s2 : s1;
    float v = w[(oc * C + ic) * 9 + tap] * (s[b * C + ic] + 1.0f)
            * d[(conv * B + b) * C + oc];
    int dst = cb * 147456
            + ((tap * 4 + (ic >> 5)) * 8 + (oc >> 4)) * 512
            + (oc & 15) * 32 + (ic & 31);
    wm[dst] = f2bs(v);
}

// ---------------------------------------------------------------------------
// dwexpand: dwm[tap][ocT=oc>>4 (16)][icC=ic>>5 (4)][(oc&15)*32+(ic&31)]
// ---------------------------------------------------------------------------
__global__ __launch_bounds__(256) void dwexpand_kernel(
    const float* __restrict__ dw, short* __restrict__ dwm)
{
    int idx = blockIdx.x * 256 + threadIdx.x;   // 16*256*128 = 524288
    int ic  = idx & 127;
    int oc  = (idx >> 7) & 255;
    int tap = idx >> 15;
    int dst = ((tap * 16 + (oc >> 4)) * 4 + (ic >> 5)) * 512
            + (oc & 15) * 32 + (ic & 31);
    dwm[dst] = f2bs(dw[(oc * C + ic) * 16 + tap]);
}

// ---------------------------------------------------------------------------
// nchw(f32) -> nhwc(bf16) transpose of features.
// ---------------------------------------------------------------------------
__global__ __launch_bounds__(256) void nchw2nhwc_kernel(
    const float* __restrict__ in, short* __restrict__ out)
{
    __shared__ short s[128 * 136];
    int bid = blockIdx.x;                   // b*128 + h
    int h = bid & 127, b = bid >> 7;
    int tid = threadIdx.x;
    for (int i = tid; i < 128 * 32; i += 256) {
        int w4 = i & 31, ic = i >> 5;
        float4 v = *(const float4*)&in[((b * C + ic) * H + h) * W + w4 * 4];
        s[(w4 * 4 + 0) * 136 + ic] = f2bs(v.x);
        s[(w4 * 4 + 1) * 136 + ic] = f2bs(v.y);
        s[(w4 * 4 + 2) * 136 + ic] = f2bs(v.z);
        s[(w4 * 4 + 3) * 136 + ic] = f2bs(v.w);
    }
    __syncthreads();
    for (int i = tid; i < 128 * 16; i += 256) {
        int icg = i & 15, w = i >> 4;
        *(uint4*)&out[((b * H + h) * W + w) * C + icg * 8] =
            *(uint4*)&s[w * 136 + icg * 8];
    }
}

// ---------------------------------------------------------------------------
// conv3x3 MFMA implicit GEMM v2.
// block tile: 128 px (8h x 16w) x 128 oc; wave: 64 px x 64 oc.
// XCD-chunked bid swizzle: each XCD's 256 blocks = 2 batches -> weights
// (2 x 295 KB) are L2-resident instead of L3 (latency 200 vs ~500 cyc).
// K pipeline: 36 steps fully unrolled; A (LDS pixels) ring-2 depth-1,
// B (global weights) ring-3 depth-2 -> ~250 MFMA cycles cover L2 latency,
// counted vmcnt instead of per-step drains. Weight walk is linear (s*4096).
// ---------------------------------------------------------------------------
__global__ __launch_bounds__(256, 3) void conv3x3_mfma(
    const short* __restrict__ in, const short* __restrict__ wmc,
    const short* __restrict__ res, short* __restrict__ out)
{
    __shared__ short sIn[10 * 18 * 136];   // 48,960 B

    int bid = blockIdx.x;
    int orig = (bid & 7) * 256 + (bid >> 3);     // XCD-chunked swizzle (2048%8==0)
    int wt = orig & 7, ht = (orig >> 3) & 15, b = orig >> 7;
    int w0 = wt * 16, h0 = ht * 8;
    int tid  = threadIdx.x;
    int lane = tid & 63, wv = tid >> 6;
    int q = lane >> 4, l15 = lane & 15;
    int wr = wv & 1;       // row half
    int wc = wv >> 1;      // oc half

    for (int i = tid; i < 10 * 18 * 16; i += 256) {
        int icg = i & 15;
        int t = i >> 4;
        int wl = t % 18, hl = t / 18;
        int gh = h0 - 1 + hl, gw = w0 - 1 + wl;
        uint4 v = make_uint4(0u, 0u, 0u, 0u);
        if ((unsigned)gh < (unsigned)H && (unsigned)gw < (unsigned)W)
            v = *(const uint4*)&in[((b * H + gh) * W + gw) * C + icg * 8];
        *(uint4*)&sIn[(hl * 18 + wl) * 136 + icg * 8] = v;
    }
    __syncthreads();

    const short* wb = wmc + b * 147456;

    f32x4 acc[4][4];
    #pragma unroll
    for (int mt = 0; mt < 4; ++mt)
        #pragma unroll
        for (int nt = 0; nt < 4; ++nt)
            acc[mt][nt] = (f32x4){0.f, 0.f, 0.f, 0.f};

    bf16x8 af[2][4];   // pixel frags, ring-2 (depth-1, LDS)
    bf16x8 bf[3][4];   // weight frags, ring-3 (depth-2, global)

    // prologue: A for step 0; B for steps 0 and 1
    #pragma unroll
    for (int mt = 0; mt < 4; ++mt)
        af[0][mt] = *(const bf16x8*)&sIn[((wr * 4 + mt) * 18 + l15) * 136 + q * 8];
    #pragma unroll
    for (int nt = 0; nt < 4; ++nt)
        bf[0][nt] = *(const bf16x8*)&wb[(wc * 4 + nt) * 512 + l15 * 32 + q * 8];
    #pragma unroll
    for (int nt = 0; nt < 4; ++nt)
        bf[1][nt] = *(const bf16x8*)&wb[4096 + (wc * 4 + nt) * 512 + l15 * 32 + q * 8];

    // main: step s = tap*4 + icChunk, tap = dh*3+dw. Fully unrolled so all
    // ring indices are compile-time (runtime-indexed ext_vector -> scratch).
    #pragma unroll
    for (int s = 0; s < 36; ++s) {
        const int s1 = (s + 1 < 36) ? s + 1 : 35;   // A prefetch target
        const int s2 = (s + 2 < 36) ? s + 2 : 35;   // B prefetch target
        const int tap1 = s1 >> 2, c1 = s1 & 3;
        const int dh1 = tap1 / 3, dw1 = tap1 % 3;
        // prefetch A (LDS) for step s+1
        #pragma unroll
        for (int mt = 0; mt < 4; ++mt)
            af[(s + 1) & 1][mt] = *(const bf16x8*)
                &sIn[((wr * 4 + mt + dh1) * 18 + l15 + dw1) * 136 + c1 * 32 + q * 8];
        // prefetch B (global, L2) for step s+2
        #pragma unroll
        for (int nt = 0; nt < 4; ++nt)
            bf[(s + 2) % 3][nt] = *(const bf16x8*)
                &wb[s2 * 4096 + (wc * 4 + nt) * 512 + l15 * 32 + q * 8];
        // compute step s
        #pragma unroll
        for (int mt = 0; mt < 4; ++mt)
            #pragma unroll
            for (int nt = 0; nt < 4; ++nt)
                acc[mt][nt] = __builtin_amdgcn_mfma_f32_16x16x32_bf16(
                    af[s & 1][mt], bf[s % 3][nt], acc[mt][nt], 0, 0, 0);
    }

    bool has_res = (res != nullptr);
    #pragma unroll
    for (int mt = 0; mt < 4; ++mt) {
        int h = h0 + wr * 4 + mt;
        #pragma unroll
        for (int nt = 0; nt < 4; ++nt) {
            int oc = wc * 64 + nt * 16 + l15;
            #pragma unroll
            for (int reg = 0; reg < 4; ++reg) {
                int w = w0 + q * 4 + reg;
                int idx = ((b * H + h) * W + w) * C + oc;
                float v = acc[mt][nt][reg];
                if (has_res) v += bs2f(res[idx]);
                v = v >= 0.f ? v : SLOPE * v;
                out[idx] = f2bs(v);
            }
        }
    }
}

// ---------------------------------------------------------------------------
// downconv MFMA v2 + XCD swizzle.
// block tile: out 4oh x 16ow x ALL 256 oc; 4 waves, each 64 oc x 64 px.
// ---------------------------------------------------------------------------
__global__ __launch_bounds__(256, 3) void downconv_mfma(
    const short* __restrict__ in, const short* __restrict__ dwm,
    const float* __restrict__ db, float* __restrict__ out)
{
    __shared__ short sIn[10 * 34 * 64];   // 43,520 B

    int bid = blockIdx.x;
    bid = (bid & 7) * 128 + (bid >> 3);          // XCD-chunked swizzle (1024%8==0)
    int wt = bid & 3;  bid >>= 2;
    int ht = bid & 15; bid >>= 4;
    int b  = bid;
    int ow0 = wt * 16, oh0 = ht * 4;
    int ih0 = 2 * oh0 - 1, iw0 = 2 * ow0 - 1;

    int tid  = threadIdx.x;
    int lane = tid & 63, wv = tid >> 6;   // wv = oc-quarter
    int q = lane >> 4, l15 = lane & 15;

    f32x4 acc[4][4];
    #pragma unroll
    for (int mt = 0; mt < 4; ++mt)
        #pragma unroll
        for (int nt = 0; nt < 4; ++nt)
            acc[mt][nt] = (f32x4){0.f, 0.f, 0.f, 0.f};

    #pragma unroll 1
    for (int s = 0; s < 2; ++s) {
        __syncthreads();               // protect sIn from prior-stage readers
        for (int i = tid; i < 10 * 34 * 8; i += 256) {
            int slot = i & 7, pix = i >> 3;
            int ihl = pix / 34, iwl = pix - ihl * 34;
            int gh = ih0 + ihl, gw = iw0 + iwl;
            uint4 v = make_uint4(0u, 0u, 0u, 0u);
            if ((unsigned)gh < (unsigned)H && (unsigned)gw < (unsigned)W)
                v = *(const uint4*)&in[((b * H + gh) * W + gw) * C + s * 64 + slot * 8];
            *(uint4*)&sIn[pix * 64 + ((slot ^ ((pix >> 1) & 7)) << 3)] = v;
        }
        __syncthreads();

        bf16x8 af[2][4], bf[2][4];
        // prologue: step 0 of this stage (tap 0: dh=0,dw=0; icC=0)
        #pragma unroll
        for (int mt = 0; mt < 4; ++mt)
            af[0][mt] = *(const bf16x8*)&dwm[((wv * 4 + mt) * 4 + s * 2) * 512
                                             + l15 * 32 + q * 8];
        #pragma unroll
        for (int nt = 0; nt < 4; ++nt) {
            int pix = (2 * nt) * 34 + 2 * l15;
            int sl  = q ^ ((pix >> 1) & 7);
            bf[0][nt] = *(const bf16x8*)&sIn[pix * 64 + sl * 8];
        }

        #pragma unroll 1
        for (int tap = 0; tap < 16; ++tap) {
            #pragma unroll
            for (int k = 0; k < 2; ++k) {          // icC within stage; parity = k
                int stepn = tap * 2 + k + 1;
                int tapn  = (stepn < 32) ? (stepn >> 1) : tap;   // dummy on last
                int kn    = (stepn < 32) ? (stepn & 1) : k;
                int dhn = tapn >> 2, dwn = tapn & 3;
                // prefetch next K-step
                #pragma unroll
                for (int mt = 0; mt < 4; ++mt)
                    af[k ^ 1][mt] = *(const bf16x8*)&dwm[((tapn * 16 + wv * 4 + mt) * 4
                                                          + s * 2 + kn) * 512
                                                         + l15 * 32 + q * 8];
                #pragma unroll
                for (int nt = 0; nt < 4; ++nt) {
                    int pix = (2 * nt + dhn) * 34 + dwn + 2 * l15;
                    int sl  = (kn * 4 + q) ^ ((pix >> 1) & 7);
                    bf[k ^ 1][nt] = *(const bf16x8*)&sIn[pix * 64 + sl * 8];
                }
                // compute current K-step
                #pragma unroll
                for (int mt = 0; mt < 4; ++mt)
                    #pragma unroll
                    for (int nt = 0; nt < 4; ++nt)
                        acc[mt][nt] = __builtin_amdgcn_mfma_f32_16x16x32_bf16(
                            af[k][mt], bf[k][nt], acc[mt][nt], 0, 0, 0);
            }
        }
    }

    // epilogue: D row = oc (q*4+reg within mt tile), col = ow (l15), nt = oh
    #pragma unroll
    for (int mt = 0; mt < 4; ++mt) {
        f32x4 bi = *(const f32x4*)&db[wv * 64 + mt * 16 + q * 4];
        #pragma unroll
        for (int nt = 0; nt < 4; ++nt) {
            int oh = oh0 + nt;
            #pragma unroll
            for (int reg = 0; reg < 4; ++reg) {
                int oc = wv * 64 + mt * 16 + q * 4 + reg;
                out[((b * CO + oc) * HO + oh) * WO + ow0 + l15] =
                    acc[mt][nt][reg] + bi[reg];
            }
        }
    }
}

// ---------------------------------------------------------------------------
extern "C" void kernel_launch(void* const* d_in, const int* in_sizes, int n_in,
                              void* d_out, int out_size, void* d_ws, size_t ws_size,
                              hipStream_t stream) {
    const float* features = (const float*)d_in[0];
    const float* sm1      = (const float*)d_in[1];   // style_mean1 -> s1
    const float* ss1      = (const float*)d_in[2];   // style_std1  -> s2 (per reference)
    const float* w1       = (const float*)d_in[6];
    const float* w2       = (const float*)d_in[7];
    const float* dw       = (const float*)d_in[8];
    const float* db       = (const float*)d_in[9];
    float* out = (float*)d_out;

    char* ws = (char*)d_ws;
    short* x1  = (short*)ws;                              // 67,108,864 B
    short* x2  = (short*)(ws + 67108864);                 // 67,108,864 B (also fx)
    short* wm  = (short*)(ws + 134217728);                // 9,437,184 B
    short* dwm = (short*)(ws + 143654912);                // 1,048,576 B
    float* dv  = (float*)(ws + 144703488);                // 16,384 B

    demod_kernel    <<<4096, 128, 0, stream>>>(w1, w2, sm1, ss1, dv);
    expand_kernel   <<<18432, 256, 0, stream>>>(w1, w2, sm1, ss1, dv, wm);
    dwexpand_kernel <<<2048, 256, 0, stream>>>(dw, dwm);
    nchw2nhwc_kernel<<<2048, 256, 0, stream>>>(features, x2);
    conv3x3_mfma    <<<2048, 256, 0, stream>>>(x2, wm, nullptr, x1);
    conv3x3_mfma    <<<2048, 256, 0, stream>>>(x1, wm + 16 * 147456, x1, x2);
    downconv_mfma   <<<1024, 256, 0, stream>>>(x2, dwm, db, out);
}

// Round 3
// 334.518 us; speedup vs baseline: 1.5363x; 1.5363x over previous
//
#include <hip/hip_runtime.h>
#include <hip/hip_bf16.h>

constexpr int B  = 16;
constexpr int C  = 128;
constexpr int H  = 128;
constexpr int W  = 128;
constexpr int CO = 256;
constexpr int HO = 64;
constexpr int WO = 64;

#define EPSV   1e-8f
#define SLOPE  0.2f

typedef short bf16x8 __attribute__((ext_vector_type(8)));
typedef float f32x4  __attribute__((ext_vector_type(4)));

typedef const __attribute__((address_space(1))) unsigned int  gbl_u32;
typedef __attribute__((address_space(3))) unsigned int        lds_u32;

__device__ __forceinline__ short f2bs(float v) {
    __hip_bfloat16 h = __float2bfloat16(v);
    return *(short*)&h;
}
__device__ __forceinline__ float bs2f(short s) {
    __hip_bfloat16 h = *(__hip_bfloat16*)&s;
    return __bfloat162float(h);
}

// ---------------------------------------------------------------------------
// demod: d[conv][b][o] = rsqrt(sum_{i,k}(w[o,i,k]*(s[b,i]+1))^2 + eps)
// ---------------------------------------------------------------------------
__global__ __launch_bounds__(128) void demod_kernel(
    const float* __restrict__ w1, const float* __restrict__ w2,
    const float* __restrict__ s1, const float* __restrict__ s2,
    float* __restrict__ d)
{
    int bid  = blockIdx.x;          // conv*2048 + b*128 + o
    int conv = bid >> 11;
    int b    = (bid >> 7) & 15;
    int o    = bid & 127;
    const float* w = conv ? w2 : w1;
    const float* s = conv ? s2 : s1;
    int i = threadIdx.x;
    float sv = s[b * C + i] + 1.0f;
    const float* wp = w + (o * C + i) * 9;
    float sum = 0.f;
    #pragma unroll
    for (int k = 0; k < 9; ++k) { float t = wp[k] * sv; sum += t * t; }
    #pragma unroll
    for (int off = 32; off; off >>= 1) sum += __shfl_down(sum, off);
    __shared__ float red[2];
    if ((threadIdx.x & 63) == 0) red[threadIdx.x >> 6] = sum;
    __syncthreads();
    if (threadIdx.x == 0) d[bid] = rsqrtf(red[0] + red[1] + EPSV);
}

// ---------------------------------------------------------------------------
// expand -> stage/step-major weight tiling for LDS staging:
// wm[cb][icH = ic>>6][step = tap*2 + icL (icL=(ic>>5)&1)][ocT=oc>>4]
//   [(oc&15)*32 + (ic&31)]   (bf16)
// one step = 8 ocT * 512 = 4096 shorts = contiguous 8 KB.
// ---------------------------------------------------------------------------
__global__ __launch_bounds__(256) void expand_kernel(
    const float* __restrict__ w1, const float* __restrict__ w2,
    const float* __restrict__ s1, const float* __restrict__ s2,
    const float* __restrict__ d, short* __restrict__ wm)
{
    int idx = blockIdx.x * 256 + threadIdx.x;
    int ic  = idx & 127;
    int oc  = (idx >> 7) & 127;
    int t   = idx >> 14;            // cb*9+tap, < 288
    int tap = t % 9;
    int cb  = t / 9;                // conv*16+b
    int b   = cb & 15;
    int conv= cb >> 4;
    const float* w = conv ? w2 : w1;
    const float* s = conv ? s2 : s1;
    float v = w[(oc * C + ic) * 9 + tap] * (s[b * C + ic] + 1.0f)
            * d[(conv * B + b) * C + oc];
    int icH = ic >> 6, icL = (ic >> 5) & 1;
    int dst = cb * 147456
            + ((icH * 18 + tap * 2 + icL) * 8 + (oc >> 4)) * 512
            + (oc & 15) * 32 + (ic & 31);
    wm[dst] = f2bs(v);
}

// ---------------------------------------------------------------------------
// dwexpand: dwm[tap][ocT=oc>>4 (16)][icC=ic>>5 (4)][(oc&15)*32+(ic&31)]
// ---------------------------------------------------------------------------
__global__ __launch_bounds__(256) void dwexpand_kernel(
    const float* __restrict__ dw, short* __restrict__ dwm)
{
    int idx = blockIdx.x * 256 + threadIdx.x;   // 16*256*128 = 524288
    int ic  = idx & 127;
    int oc  = (idx >> 7) & 255;
    int tap = idx >> 15;
    int dst = ((tap * 16 + (oc >> 4)) * 4 + (ic >> 5)) * 512
            + (oc & 15) * 32 + (ic & 31);
    dwm[dst] = f2bs(dw[(oc * C + ic) * 16 + tap]);
}

// ---------------------------------------------------------------------------
// nchw(f32) -> nhwc(bf16) transpose of features.
// ---------------------------------------------------------------------------
__global__ __launch_bounds__(256) void nchw2nhwc_kernel(
    const float* __restrict__ in, short* __restrict__ out)
{
    __shared__ short s[128 * 136];
    int bid = blockIdx.x;                   // b*128 + h
    int h = bid & 127, b = bid >> 7;
    int tid = threadIdx.x;
    for (int i = tid; i < 128 * 32; i += 256) {
        int w4 = i & 31, ic = i >> 5;
        float4 v = *(const float4*)&in[((b * C + ic) * H + h) * W + w4 * 4];
        s[(w4 * 4 + 0) * 136 + ic] = f2bs(v.x);
        s[(w4 * 4 + 1) * 136 + ic] = f2bs(v.y);
        s[(w4 * 4 + 2) * 136 + ic] = f2bs(v.z);
        s[(w4 * 4 + 3) * 136 + ic] = f2bs(v.w);
    }
    __syncthreads();
    for (int i = tid; i < 128 * 16; i += 256) {
        int icg = i & 15, w = i >> 4;
        *(uint4*)&out[((b * H + h) * W + w) * C + icg * 8] =
            *(uint4*)&s[w * 136 + icg * 8];
    }
}

// ---------------------------------------------------------------------------
// conv3x3 MFMA implicit GEMM v3 — m97-shaped schedule.
// block tile: 128 px (8h x 16w) x 128 oc; wave: 64 px x 64 oc.
// Input: 2 ic-stages of 64; sIn pix-major [180 px][64 ic], 16B slots
//   XOR-swizzled by pix&7 -> every LDS access is uniform (b128 minimum).
// Weights: per-step 8 KB block staged to double-buffered LDS via
//   global_load_lds width-16 (linear dest); one barrier per K-step;
//   next step's loads are in flight across ds_reads + 16 MFMAs.
// LDS 23,040 + 16,384 = 39,424 B -> 4 blocks/CU.
// ---------------------------------------------------------------------------
__global__ __launch_bounds__(256, 4) void conv3x3_mfma(
    const short* __restrict__ in, const short* __restrict__ wmc,
    const short* __restrict__ res, short* __restrict__ out)
{
    __shared__ short sIn[180 * 64];     // 23,040 B
    __shared__ short sW[2][4096];       // 16,384 B

    int bid = blockIdx.x;
    int wt = bid & 7, ht = (bid >> 3) & 15, b = bid >> 7;
    int w0 = wt * 16, h0 = ht * 8;
    int tid  = threadIdx.x;
    int lane = tid & 63, wv = tid >> 6;
    int q = lane >> 4, l15 = lane & 15;
    int wr = wv & 1;       // row half
    int wc = wv >> 1;      // oc half

    const short* wb = wmc + b * 147456;

    // ---- helpers -----------------------------------------------------------
    auto stageIn = [&](int st) {       // stage 64-ic half `st` of the halo
        for (int i = tid; i < 180 * 8; i += 256) {
            int slot = i & 7, pix = i >> 3;
            int hl = pix / 18, wl = pix - hl * 18;
            int gh = h0 - 1 + hl, gw = w0 - 1 + wl;
            uint4 v = make_uint4(0u, 0u, 0u, 0u);
            if ((unsigned)gh < (unsigned)H && (unsigned)gw < (unsigned)W)
                v = *(const uint4*)&in[((b * H + gh) * W + gw) * C + st * 64 + slot * 8];
            *(uint4*)&sIn[pix * 64 + ((slot ^ (pix & 7)) << 3)] = v;
        }
    };
    auto stageW = [&](int st, int s, int buf) {   // 8 KB step -> sW[buf]
        #pragma unroll
        for (int i = 0; i < 2; ++i) {
            const short* g = wb + st * 73728 + s * 4096
                           + (wv * 2 + i) * 512 + lane * 8;
            __builtin_amdgcn_global_load_lds(
                (gbl_u32*)g, (lds_u32*)&sW[buf][(wv * 2 + i) * 512], 16, 0, 0);
        }
    };
    // -----------------------------------------------------------------------

    f32x4 acc[4][4];
    #pragma unroll
    for (int mt = 0; mt < 4; ++mt)
        #pragma unroll
        for (int nt = 0; nt < 4; ++nt)
            acc[mt][nt] = (f32x4){0.f, 0.f, 0.f, 0.f};

    stageIn(0);
    stageW(0, 0, 0);
    __syncthreads();

    int bfbase = l15 * 32 + q * 8;

    #pragma unroll 1
    for (int st = 0; st < 2; ++st) {
        #pragma unroll 2
        for (int s = 0; s < 18; ++s) {
            int tap = s >> 1, icL = s & 1;
            int dh = tap / 3, dwd = tap - dh * 3;
            // issue next step's weight staging (in flight across this step)
            if (s < 17)        stageW(st, s + 1, (s + 1) & 1);
            else if (st == 0)  stageW(1, 0, 0);     // (18 even -> buf 0)
            // fragments
            bf16x8 af[4], bf[4];
            #pragma unroll
            for (int mt = 0; mt < 4; ++mt) {
                int pix  = (wr * 4 + mt + dh) * 18 + l15 + dwd;
                int slot = (icL * 4 + q) ^ (pix & 7);
                af[mt] = *(const bf16x8*)&sIn[pix * 64 + slot * 8];
            }
            #pragma unroll
            for (int nt = 0; nt < 4; ++nt)
                bf[nt] = *(const bf16x8*)&sW[s & 1][(wc * 4 + nt) * 512 + bfbase];
            // compute
            #pragma unroll
            for (int mt = 0; mt < 4; ++mt)
                #pragma unroll
                for (int nt = 0; nt < 4; ++nt)
                    acc[mt][nt] = __builtin_amdgcn_mfma_f32_16x16x32_bf16(
                        af[mt], bf[nt], acc[mt][nt], 0, 0, 0);
            __syncthreads();   // next buf loaded; this buf free to overwrite
        }
        if (st == 0) { stageIn(1); __syncthreads(); }
    }

    bool has_res = (res != nullptr);
    #pragma unroll
    for (int mt = 0; mt < 4; ++mt) {
        int h = h0 + wr * 4 + mt;
        #pragma unroll
        for (int nt = 0; nt < 4; ++nt) {
            int oc = wc * 64 + nt * 16 + l15;
            #pragma unroll
            for (int reg = 0; reg < 4; ++reg) {
                int w = w0 + q * 4 + reg;
                int idx = ((b * H + h) * W + w) * C + oc;
                float v = acc[mt][nt][reg];
                if (has_res) v += bs2f(res[idx]);
                v = v >= 0.f ? v : SLOPE * v;
                out[idx] = f2bs(v);
            }
        }
    }
}

// ---------------------------------------------------------------------------
// downconv MFMA v2 (no XCD swizzle — swizzle proven harmful in r2).
// block tile: out 4oh x 16ow x ALL 256 oc; 4 waves, each 64 oc x 64 px.
// ---------------------------------------------------------------------------
__global__ __launch_bounds__(256, 3) void downconv_mfma(
    const short* __restrict__ in, const short* __restrict__ dwm,
    const float* __restrict__ db, float* __restrict__ out)
{
    __shared__ short sIn[10 * 34 * 64];   // 43,520 B

    int bid = blockIdx.x;
    int wt = bid & 3;  bid >>= 2;
    int ht = bid & 15; bid >>= 4;
    int b  = bid;
    int ow0 = wt * 16, oh0 = ht * 4;
    int ih0 = 2 * oh0 - 1, iw0 = 2 * ow0 - 1;

    int tid  = threadIdx.x;
    int lane = tid & 63, wv = tid >> 6;   // wv = oc-quarter
    int q = lane >> 4, l15 = lane & 15;

    f32x4 acc[4][4];
    #pragma unroll
    for (int mt = 0; mt < 4; ++mt)
        #pragma unroll
        for (int nt = 0; nt < 4; ++nt)
            acc[mt][nt] = (f32x4){0.f, 0.f, 0.f, 0.f};

    #pragma unroll 1
    for (int s = 0; s < 2; ++s) {
        __syncthreads();               // protect sIn from prior-stage readers
        for (int i = tid; i < 10 * 34 * 8; i += 256) {
            int slot = i & 7, pix = i >> 3;
            int ihl = pix / 34, iwl = pix - ihl * 34;
            int gh = ih0 + ihl, gw = iw0 + iwl;
            uint4 v = make_uint4(0u, 0u, 0u, 0u);
            if ((unsigned)gh < (unsigned)H && (unsigned)gw < (unsigned)W)
                v = *(const uint4*)&in[((b * H + gh) * W + gw) * C + s * 64 + slot * 8];
            *(uint4*)&sIn[pix * 64 + ((slot ^ ((pix >> 1) & 7)) << 3)] = v;
        }
        __syncthreads();

        bf16x8 af[2][4], bf[2][4];
        // prologue: step 0 of this stage (tap 0: dh=0,dw=0; icC=0)
        #pragma unroll
        for (int mt = 0; mt < 4; ++mt)
            af[0][mt] = *(const bf16x8*)&dwm[((wv * 4 + mt) * 4 + s * 2) * 512
                                             + l15 * 32 + q * 8];
        #pragma unroll
        for (int nt = 0; nt < 4; ++nt) {
            int pix = (2 * nt) * 34 + 2 * l15;
            int sl  = q ^ ((pix >> 1) & 7);
            bf[0][nt] = *(const bf16x8*)&sIn[pix * 64 + sl * 8];
        }

        #pragma unroll 1
        for (int tap = 0; tap < 16; ++tap) {
            #pragma unroll
            for (int k = 0; k < 2; ++k) {          // icC within stage; parity = k
                int stepn = tap * 2 + k + 1;
                int tapn  = (stepn < 32) ? (stepn >> 1) : tap;   // dummy on last
                int kn    = (stepn < 32) ? (stepn & 1) : k;
                int dhn = tapn >> 2, dwn = tapn & 3;
                // prefetch next K-step
                #pragma unroll
                for (int mt = 0; mt < 4; ++mt)
                    af[k ^ 1][mt] = *(const bf16x8*)&dwm[((tapn * 16 + wv * 4 + mt) * 4
                                                          + s * 2 + kn) * 512
                                                         + l15 * 32 + q * 8];
                #pragma unroll
                for (int nt = 0; nt < 4; ++nt) {
                    int pix = (2 * nt + dhn) * 34 + dwn + 2 * l15;
                    int sl  = (kn * 4 + q) ^ ((pix >> 1) & 7);
                    bf[k ^ 1][nt] = *(const bf16x8*)&sIn[pix * 64 + sl * 8];
                }
                // compute current K-step
                #pragma unroll
                for (int mt = 0; mt < 4; ++mt)
                    #pragma unroll
                    for (int nt = 0; nt < 4; ++nt)
                        acc[mt][nt] = __builtin_amdgcn_mfma_f32_16x16x32_bf16(
                            af[k][mt], bf[k][nt], acc[mt][nt], 0, 0, 0);
            }
        }
    }

    // epilogue: D row = oc (q*4+reg within mt tile), col = ow (l15), nt = oh
    #pragma unroll
    for (int mt = 0; mt < 4; ++mt) {
        f32x4 bi = *(const f32x4*)&db[wv * 64 + mt * 16 + q * 4];
        #pragma unroll
        for (int nt = 0; nt < 4; ++nt) {
            int oh = oh0 + nt;
            #pragma unroll
            for (int reg = 0; reg < 4; ++reg) {
                int oc = wv * 64 + mt * 16 + q * 4 + reg;
                out[((b * CO + oc) * HO + oh) * WO + ow0 + l15] =
                    acc[mt][nt][reg] + bi[reg];
            }
        }
    }
}

// ---------------------------------------------------------------------------
extern "C" void kernel_launch(void* const* d_in, const int* in_sizes, int n_in,
                              void* d_out, int out_size, void* d_ws, size_t ws_size,
                              hipStream_t stream) {
    const float* features = (const float*)d_in[0];
    const float* sm1      = (const float*)d_in[1];   // style_mean1 -> s1
    const float* ss1      = (const float*)d_in[2];   // style_std1  -> s2 (per reference)
    const float* w1       = (const float*)d_in[6];
    const float* w2       = (const float*)d_in[7];
    const float* dw       = (const float*)d_in[8];
    const float* db       = (const float*)d_in[9];
    float* out = (float*)d_out;

    char* ws = (char*)d_ws;
    short* x1  = (short*)ws;                              // 67,108,864 B
    short* x2  = (short*)(ws + 67108864);                 // 67,108,864 B (also fx)
    short* wm  = (short*)(ws + 134217728);                // 9,437,184 B
    short* dwm = (short*)(ws + 143654912);                // 1,048,576 B
    float* dv  = (float*)(ws + 144703488);                // 16,384 B

    demod_kernel    <<<4096, 128, 0, stream>>>(w1, w2, sm1, ss1, dv);
    expand_kernel   <<<18432, 256, 0, stream>>>(w1, w2, sm1, ss1, dv, wm);
    dwexpand_kernel <<<2048, 256, 0, stream>>>(dw, dwm);
    nchw2nhwc_kernel<<<2048, 256, 0, stream>>>(features, x2);
    conv3x3_mfma    <<<2048, 256, 0, stream>>>(x2, wm, nullptr, x1);
    conv3x3_mfma    <<<2048, 256, 0, stream>>>(x1, wm + 16 * 147456, x1, x2);
    downconv_mfma   <<<1024, 256, 0, stream>>>(x2, dwm, db, out);
}